// Round 10
// baseline (672.579 us; speedup 1.0000x reference)
//
#include <hip/hip_runtime.h>
#include <hip/hip_bf16.h>

#define B_ 32
#define S_ 2048
#define D_ 1024
#define H_ 512
#define M_ (B_*S_)    // 65536
#define BM 128
#define BN 256
#define BK 64
#define TILE_A (BM*BK)   // 8192 shorts = 16 KB
#define TILE_B (BN*BK)   // 16384 shorts = 32 KB

typedef __attribute__((ext_vector_type(8))) short short8;
typedef __attribute__((ext_vector_type(4))) float f32x4;

__device__ __forceinline__ unsigned short f2bf(float f){
  return __builtin_bit_cast(unsigned short, __float2bfloat16(f));  // RNE packed cvt
}

__device__ __forceinline__ float fast_tanh(float x){
  return 1.f - 2.f*__builtin_amdgcn_rcpf(__expf(2.f*x) + 1.f);
}

// XOR swizzle for [rows][64] bf16 LDS tiles, 16B granularity (0 conflicts R4-R8).
__device__ __forceinline__ int swz(int row, int kshort){
  return row*BK + ((kshort & 56) ^ ((row&7)<<3)) + (kshort & 7);
}

// ---------------- kernel W: W1 fp32 -> bf16, 256-row-tile-major PRE-SWIZZLED -----
__global__ __launch_bounds__(256) void convw_kernel(
    const float* __restrict__ W1, unsigned short* __restrict__ W1s){
  int g = blockIdx.x*256 + threadIdx.x;   // one thread per 8 elems
  int n = g*8;
  int h = n >> 10, k = n & 1023;
  int bn = h >> 8, row = h & 255;
  int kt = k >> 6, kk = k & 63;
  float4 lo = *(const float4*)(W1 + n);
  float4 hi = *(const float4*)(W1 + n + 4);
  short8 r;
  r[0]=(short)f2bf(lo.x); r[1]=(short)f2bf(lo.y); r[2]=(short)f2bf(lo.z); r[3]=(short)f2bf(lo.w);
  r[4]=(short)f2bf(hi.x); r[5]=(short)f2bf(hi.y); r[6]=(short)f2bf(hi.z); r[7]=(short)f2bf(hi.w);
  *(short8*)&W1s[(size_t)(bn*16 + kt)*TILE_B + swz(row, kk)] = r;
}

// ---------------- kernel 0: qbias (R1 form — measured 9.9 us) --------------------
__global__ __launch_bounds__(256) void qbias_kernel(
    const float* __restrict__ hidden, const float* __restrict__ W2,
    const float* __restrict__ W1b, const float* __restrict__ W2b,
    float* __restrict__ qb){
  int b = blockIdx.x, h0 = blockIdx.y*64;
  int wave = threadIdx.x>>6, lane = threadIdx.x&63;
  const float* q = hidden + (size_t)(B_ + b)*D_;   // hidden[-1]
  for (int i=0;i<16;i++){
    int h = h0 + wave*16 + i;
    const float* w = W2 + (size_t)h*D_;
    float s = 0.f;
    #pragma unroll
    for (int it=0; it<4; ++it){
      int d = it*256 + lane*4;
      const float4 qq = *(const float4*)(q+d);
      const float4 ww = *(const float4*)(w+d);
      s += qq.x*ww.x + qq.y*ww.y + qq.z*ww.z + qq.w*ww.w;
    }
    #pragma unroll
    for (int off=1; off<64; off<<=1) s += __shfl_xor(s, off);
    if (lane==0) qb[b*H_ + h] = s + W1b[h] + W2b[h];
  }
}

// ---------------- kernel 1: fused score GEMM — BN=256 fat waves ------------------
// 4 waves, wave-tile 64x128, acc 4x8.  R7 schedule (proven): COMPUTE | bar |
// GLD_B(kt+2)->freed Bs[p] | CVT_A(kt+1)->As | LOAD_A(kt+2) | lgkm | bar.
// LDS: As 16K + Bs 2x32K = 80KB -> 2 blocks/CU; psum aliased into As after loop.
__global__ __launch_bounds__(256, 2) void score_gemm(
    const float* __restrict__ enc, const unsigned short* __restrict__ W1s,
    const float* __restrict__ qb, const float* __restrict__ Vw,
    float* __restrict__ score_p){
  const int id  = blockIdx.x;
  const int xcd = id & 7;
  const int j   = id >> 3;               // 0..127
  const int bm  = xcd*64 + (j >> 1);     // 0..511; bn-pair adjacent -> same XCD
  const int bn  = j & 1;                 // 0..1
  const int m0 = bm*BM, h0 = bn*BN;
  const int tid = threadIdx.x, lane = tid&63, wave = tid>>6;
  const int wm = (wave>>1)*64, wn = (wave&1)*128;

  __shared__ __align__(16) unsigned short lds[TILE_A + 2*TILE_B];  // 80 KB
  unsigned short* As = lds;
  unsigned short* Bs0 = lds + TILE_A;
  unsigned short* Bs1 = lds + TILE_A + TILE_B;
  float* psum = (float*)lds;             // aliased; used only after K-loop

  f32x4 acc[4][8];
  #pragma unroll
  for (int i=0;i<4;i++)
    #pragma unroll
    for (int j2=0;j2<8;j2++)
      acc[i][j2] = (f32x4)(0.f);

  float4 aLo[4], aHi[4];

#define LOAD_A(KT) do{ const int kkx=(KT)*BK; \
  _Pragma("unroll") for (int i=0;i<4;i++){ \
    int c=tid+i*256; int row=c>>3, kc=(c&7)*8; \
    const float4* pa=(const float4*)(enc+(size_t)(m0+row)*D_+kkx+kc); \
    aLo[i]=pa[0]; aHi[i]=pa[1]; } }while(0)

#define GLD_B(KT,BP) do{ const unsigned short* bsrc=W1s+(size_t)(bn*16+(KT))*TILE_B; \
  _Pragma("unroll") for (int i=0;i<8;i++){ \
    __builtin_amdgcn_global_load_lds( \
      (const __attribute__((address_space(1))) unsigned int*)(bsrc+i*2048+tid*8), \
      (__attribute__((address_space(3))) unsigned int*)&(BP)[i*2048+tid*8], 16,0,0); } }while(0)

#define CVT_A() do{ \
  _Pragma("unroll") for (int i=0;i<4;i++){ \
    int c=tid+i*256; int row=c>>3, kc=(c&7)*8; short8 av; \
    av[0]=(short)f2bf(aLo[i].x); av[1]=(short)f2bf(aLo[i].y); \
    av[2]=(short)f2bf(aLo[i].z); av[3]=(short)f2bf(aLo[i].w); \
    av[4]=(short)f2bf(aHi[i].x); av[5]=(short)f2bf(aHi[i].y); \
    av[6]=(short)f2bf(aHi[i].z); av[7]=(short)f2bf(aHi[i].w); \
    *(short8*)&As[swz(row,kc)] = av; } }while(0)

#define COMPUTE(BP) do{ \
  _Pragma("unroll") for (int kh=0; kh<2; ++kh){ \
    const int kb = kh*32 + (lane>>4)*8; \
    short8 af[4]; \
    _Pragma("unroll") for (int mi=0;mi<4;mi++){ \
      int row=wm+mi*16+(lane&15); af[mi]=*(const short8*)&As[swz(row,kb)]; } \
    _Pragma("unroll") for (int ni=0;ni<8;ni++){ \
      int row=wn+ni*16+(lane&15); \
      short8 bf=*(const short8*)&(BP)[swz(row,kb)]; \
      _Pragma("unroll") for (int mi=0;mi<4;mi++) \
        acc[mi][ni]=__builtin_amdgcn_mfma_f32_16x16x32_bf16(af[mi],bf,acc[mi][ni],0,0,0); \
    } \
  } }while(0)

  // ---- prologue: As=A0, Bs0=B0 (drained); A1 + B1 in flight
  LOAD_A(0);                                   // A0:8
  GLD_B(0, Bs0);                               // B0:8
  CVT_A();                                     // auto-wait A0 (B0 stays)
  LOAD_A(1);                                   // A1:8
  GLD_B(1, Bs1);                               // B1:8
  asm volatile("s_waitcnt vmcnt(16) lgkmcnt(0)" ::: "memory"); // B0 + As writes done
  __builtin_amdgcn_s_barrier();

  // ---- steady: kt = 0..13
  for (int kt=0; kt<14; ++kt){
    if (kt&1) COMPUTE(Bs1); else COMPUTE(Bs0);   // Bs[kt&1] = B(kt)
    __builtin_amdgcn_s_barrier();                // reads of As & Bs[p] done
    if (kt&1) GLD_B(kt+2, Bs1); else GLD_B(kt+2, Bs0);  // refill freed buffer
    CVT_A();                                     // auto-wait A(kt+1) (drains B(kt+1) too)
    LOAD_A(kt+2);
    asm volatile("s_waitcnt lgkmcnt(0)" ::: "memory");
    __builtin_amdgcn_s_barrier();
  }
  // ---- tail kt=14
  COMPUTE(Bs0);                                // B14
  __builtin_amdgcn_s_barrier();
  CVT_A();                                     // waits A15 -> drains B15
  asm volatile("s_waitcnt lgkmcnt(0)" ::: "memory");
  __builtin_amdgcn_s_barrier();
  // ---- tail kt=15
  COMPUTE(Bs1);                                // B15

  // ---- epilogue: fast-tanh + V_w reduce -> per-bn partial score ----------------
  const int bidx = m0 >> 11;
  float qv[8], vwv[8];
  #pragma unroll
  for (int ni=0;ni<8;ni++){
    int h = h0 + wn + ni*16 + (lane&15);
    qv[ni]  = qb[bidx*H_ + h];
    vwv[ni] = Vw[h];
  }
  __builtin_amdgcn_s_barrier();                // As reads long done; reuse as psum
  #pragma unroll
  for (int mi=0;mi<4;mi++){
    #pragma unroll
    for (int r=0;r<4;r++){
      float s = 0.f;
      #pragma unroll
      for (int ni=0;ni<8;ni++) s += fast_tanh(acc[mi][ni][r] + qv[ni]) * vwv[ni];
      s += __shfl_xor(s,1); s += __shfl_xor(s,2);
      s += __shfl_xor(s,4); s += __shfl_xor(s,8);
      if ((lane&15)==0){
        int m = wm + mi*16 + ((lane>>4)<<2) + r;  // 0..127
        psum[wave*BM + m] = s;
      }
    }
  }
  __syncthreads();
  if (tid < BM){
    int w0 = (tid>>6)*2;   // rows 0-63 -> waves 0,1; rows 64-127 -> waves 2,3
    score_p[(size_t)bn*M_ + m0 + tid] = psum[w0*BM + tid] + psum[(w0+1)*BM + tid];
  }
}

// ---------------- kernel 2: masked softmax over S (sums 2 bn partials) -----------
__global__ __launch_bounds__(256) void softmax_kernel(
    const float* __restrict__ score_p, const int* __restrict__ mask,
    float* __restrict__ attn){
  int b = blockIdx.x, tid = threadIdx.x;
  int wave = tid>>6, lane = tid&63;
  __shared__ float red[8];
  float v[8];
  float mx = -1e30f;
  #pragma unroll
  for (int i=0;i<8;i++){
    int idx = b*S_ + tid + i*256;
    float sc = score_p[idx] + score_p[M_+idx];
    v[i] = (mask[idx]==0) ? -1e9f : sc;
    mx = fmaxf(mx, v[i]);
  }
  #pragma unroll
  for (int off=1; off<64; off<<=1) mx = fmaxf(mx, __shfl_xor(mx, off));
  if (lane==0) red[wave] = mx;
  __syncthreads();
  mx = fmaxf(fmaxf(red[0],red[1]), fmaxf(red[2],red[3]));
  float sum = 0.f;
  #pragma unroll
  for (int i=0;i<8;i++){ v[i] = __expf(v[i]-mx); sum += v[i]; }
  #pragma unroll
  for (int off=1; off<64; off<<=1) sum += __shfl_xor(sum, off);
  if (lane==0) red[4+wave] = sum;
  __syncthreads();
  float inv = 1.f/(red[4]+red[5]+red[6]+red[7]);
  #pragma unroll
  for (int i=0;i<8;i++) attn[b*S_ + tid + i*256] = v[i]*inv;
}

// ---------------- kernel 3a: context partials (NO atomics) -----------------------
__global__ __launch_bounds__(256) void context_part(
    const float* __restrict__ enc, const float* __restrict__ attn,
    float* __restrict__ ctx_p){
  int b = blockIdx.x, sc = blockIdx.y;        // 32 s-chunks of 64 rows
  int s0 = sc*64;
  int d4 = threadIdx.x*4;
  const float* ep = enc + ((size_t)b*S_ + s0)*D_ + d4;
  const float* ap = attn + b*S_ + s0;
  float4 a0 = make_float4(0.f,0.f,0.f,0.f);
  float4 a1 = make_float4(0.f,0.f,0.f,0.f);
  #pragma unroll 4
  for (int i=0;i<64;i+=2){
    float w0 = ap[i], w1 = ap[i+1];
    float4 e0 = *(const float4*)(ep + (size_t)i*D_);
    float4 e1 = *(const float4*)(ep + (size_t)(i+1)*D_);
    a0.x = fmaf(w0, e0.x, a0.x); a0.y = fmaf(w0, e0.y, a0.y);
    a0.z = fmaf(w0, e0.z, a0.z); a0.w = fmaf(w0, e0.w, a0.w);
    a1.x = fmaf(w1, e1.x, a1.x); a1.y = fmaf(w1, e1.y, a1.y);
    a1.z = fmaf(w1, e1.z, a1.z); a1.w = fmaf(w1, e1.w, a1.w);
  }
  float4 t = make_float4(a0.x+a1.x, a0.y+a1.y, a0.z+a1.z, a0.w+a1.w);
  *(float4*)(ctx_p + ((size_t)b*32 + sc)*D_ + d4) = t;
}

// ---------------- kernel 3b: reduce 32 partials -> ctx ---------------------------
__global__ __launch_bounds__(256) void context_reduce(
    const float* __restrict__ ctx_p, float* __restrict__ ctx){
  int b = blockIdx.x;
  int d4 = threadIdx.x*4;
  f32x4 s = (f32x4)(0.f);
  #pragma unroll 8
  for (int sc=0; sc<32; ++sc)
    s += *(const f32x4*)(ctx_p + ((size_t)b*32 + sc)*D_ + d4);
  *(f32x4*)(ctx + (size_t)b*D_ + d4) = s;
}

extern "C" void kernel_launch(void* const* d_in, const int* in_sizes, int n_in,
                              void* d_out, int out_size, void* d_ws, size_t ws_size,
                              hipStream_t stream){
  const float* hidden = (const float*)d_in[0];
  const float* enc    = (const float*)d_in[1];
  const int*   mask   = (const int*)d_in[2];
  const float* W1w    = (const float*)d_in[3];
  const float* W1b    = (const float*)d_in[4];
  const float* W2w    = (const float*)d_in[5];
  const float* W2b    = (const float*)d_in[6];
  const float* Vw     = (const float*)d_in[7];
  // V_b (d_in[8]) provably cancels in softmax — unused.
  float* out = (float*)d_out;

  float* qb           = (float*)d_ws;                      // 64 KB
  float* score_p      = qb + B_*H_;                        // 2*M_ f32 = 512 KB
  unsigned short* W1s = (unsigned short*)(score_p + 2*M_); // 1 MB bf16 pre-swizzled
  float* ctx_p        = (float*)(W1s + H_*D_);             // 32*32*1024 f32 = 4 MB

  convw_kernel  <<<H_*D_/8/256,     256, 0, stream>>>(W1w, W1s);
  qbias_kernel  <<<dim3(B_, H_/64), 256, 0, stream>>>(hidden, W2w, W1b, W2b, qb);
  score_gemm    <<<2*(M_/BM),       256, 0, stream>>>(enc, W1s, qb, Vw, score_p);
  softmax_kernel<<<B_,              256, 0, stream>>>(score_p, mask, out + B_*D_);
  context_part  <<<dim3(B_, 32),    256, 0, stream>>>(enc, out + B_*D_, ctx_p);
  context_reduce<<<B_,              256, 0, stream>>>(ctx_p, out);
}

// Round 12
// 176.737 us; speedup vs baseline: 3.8055x; 3.8055x over previous
//
#include <hip/hip_runtime.h>
#include <hip/hip_bf16.h>

#define B_ 32
#define S_ 2048
#define D_ 1024
#define H_ 512
#define M_ (B_*S_)   // 65536
#define BM 128
#define BN 128
#define BK 64
#define TILE (BM*BK) // 8192 shorts = 16 KB

typedef __attribute__((ext_vector_type(8))) short short8;
typedef __attribute__((ext_vector_type(4))) float f32x4;

__device__ __forceinline__ unsigned short f2bf(float f){
  return __builtin_bit_cast(unsigned short, __float2bfloat16(f));  // RNE packed cvt
}

__device__ __forceinline__ float fast_tanh(float x){
  return 1.f - 2.f*__builtin_amdgcn_rcpf(__expf(2.f*x) + 1.f);
}

// XOR swizzle for a [128][64] bf16 LDS tile, 16B granularity (0 conflicts R4-R8).
__device__ __forceinline__ int swz(int row, int kshort){
  return row*BK + ((kshort & 56) ^ ((row&7)<<3)) + (kshort & 7);
}

// ---------------- kernel W: W1 fp32 -> bf16, tile-major PRE-SWIZZLED -------------
__global__ __launch_bounds__(256) void convw_kernel(
    const float* __restrict__ W1, unsigned short* __restrict__ W1s){
  int tid = blockIdx.x*256 + threadIdx.x;
  int n = tid*8;
  int h = n >> 10;
  int k = n & 1023;
  int bn = h >> 7, row = h & 127;
  int kt = k >> 6, kk = k & 63;
  float4 lo = *(const float4*)(W1 + n);
  float4 hi = *(const float4*)(W1 + n + 4);
  short8 r;
  r[0]=(short)f2bf(lo.x); r[1]=(short)f2bf(lo.y); r[2]=(short)f2bf(lo.z); r[3]=(short)f2bf(lo.w);
  r[4]=(short)f2bf(hi.x); r[5]=(short)f2bf(hi.y); r[6]=(short)f2bf(hi.z); r[7]=(short)f2bf(hi.w);
  *(short8*)&W1s[(bn*16 + kt)*TILE + swz(row, kk)] = r;
}

// ---------------- kernel 0: qbias (R1 form — measured 9.9 us) --------------------
__global__ __launch_bounds__(256) void qbias_kernel(
    const float* __restrict__ hidden, const float* __restrict__ W2,
    const float* __restrict__ W1b, const float* __restrict__ W2b,
    float* __restrict__ qb){
  int b = blockIdx.x, h0 = blockIdx.y*64;
  int wave = threadIdx.x>>6, lane = threadIdx.x&63;
  const float* q = hidden + (size_t)(B_ + b)*D_;   // hidden[-1]
  for (int i=0;i<16;i++){
    int h = h0 + wave*16 + i;
    const float* w = W2 + (size_t)h*D_;
    float s = 0.f;
    #pragma unroll
    for (int it=0; it<4; ++it){
      int d = it*256 + lane*4;
      const float4 qq = *(const float4*)(q+d);
      const float4 ww = *(const float4*)(w+d);
      s += qq.x*ww.x + qq.y*ww.y + qq.z*ww.z + qq.w*ww.w;
    }
    #pragma unroll
    for (int off=1; off<64; off<<=1) s += __shfl_xor(s, off);
    if (lane==0) qb[b*H_ + h] = s + W1b[h] + W2b[h];
  }
}

// ---------------- kernel 1: fused score GEMM (R7 verbatim — best measured) -------
// Single-buffer As (16K) + double-buffer Bs (32K) = 48K -> 3 blocks/CU.
// Schedule: COMPUTE(kt) | bar | GLD_B(kt+2) CVT_A(kt+1) LOAD_A(kt+2) | lgkm bar.
__global__ __launch_bounds__(256, 3) void score_gemm(
    const float* __restrict__ enc, const unsigned short* __restrict__ W1s,
    const float* __restrict__ qb, const float* __restrict__ Vw,
    float* __restrict__ score_p){
  const int id  = blockIdx.x;
  const int xcd = id & 7;
  const int j   = id >> 3;
  const int bm  = xcd*64 + (j >> 2);    // 4 same-bm blocks on same XCD (R5)
  const int bn  = j & 3;
  const int m0 = bm*BM, h0 = bn*BN;
  const int tid = threadIdx.x, lane = tid&63, wave = tid>>6;
  const int wm = (wave>>1)*64, wn = (wave&1)*64;

  __shared__ __align__(16) unsigned short As[TILE];      // 16 KB
  __shared__ __align__(16) unsigned short Bs[2][TILE];   // 32 KB

  f32x4 acc[4][4];
  #pragma unroll
  for (int i=0;i<4;i++)
    #pragma unroll
    for (int j2=0;j2<4;j2++)
      acc[i][j2] = (f32x4)(0.f);

  float4 aLo[4], aHi[4];

#define LOAD_A(KT) do{ const int kkx=(KT)*BK; \
  _Pragma("unroll") for (int i=0;i<4;i++){ \
    int c=tid+i*256; int row=c>>3, kc=(c&7)*8; \
    const float4* pa=(const float4*)(enc+(size_t)(m0+row)*D_+kkx+kc); \
    aLo[i]=pa[0]; aHi[i]=pa[1]; } }while(0)

#define GLD_B(KT,P) do{ const unsigned short* bsrc=W1s+(size_t)(bn*16+(KT))*TILE; \
  _Pragma("unroll") for (int i=0;i<4;i++){ \
    __builtin_amdgcn_global_load_lds( \
      (const __attribute__((address_space(1))) unsigned int*)(bsrc+i*2048+tid*8), \
      (__attribute__((address_space(3))) unsigned int*)&Bs[P][i*2048+tid*8], 16,0,0); } }while(0)

#define CVT_A() do{ \
  _Pragma("unroll") for (int i=0;i<4;i++){ \
    int c=tid+i*256; int row=c>>3, kc=(c&7)*8; short8 av; \
    av[0]=(short)f2bf(aLo[i].x); av[1]=(short)f2bf(aLo[i].y); \
    av[2]=(short)f2bf(aLo[i].z); av[3]=(short)f2bf(aLo[i].w); \
    av[4]=(short)f2bf(aHi[i].x); av[5]=(short)f2bf(aHi[i].y); \
    av[6]=(short)f2bf(aHi[i].z); av[7]=(short)f2bf(aHi[i].w); \
    *(short8*)&As[swz(row,kc)] = av; } }while(0)

#define COMPUTE(P) do{ \
  _Pragma("unroll") for (int kh=0; kh<2; ++kh){ \
    const int kb = kh*32 + (lane>>4)*8; \
    short8 af[4], bf[4]; \
    _Pragma("unroll") for (int mi=0;mi<4;mi++){ \
      int row=wm+mi*16+(lane&15); af[mi]=*(const short8*)&As[swz(row,kb)]; } \
    _Pragma("unroll") for (int ni=0;ni<4;ni++){ \
      int row=wn+ni*16+(lane&15); bf[ni]=*(const short8*)&Bs[P][swz(row,kb)]; } \
    _Pragma("unroll") for (int mi=0;mi<4;mi++) \
      _Pragma("unroll") for (int ni=0;ni<4;ni++) \
        acc[mi][ni]=__builtin_amdgcn_mfma_f32_16x16x32_bf16(af[mi],bf[ni],acc[mi][ni],0,0,0); \
  } }while(0)

  // ---- prologue: As=tile0, Bs[0]=B0 (drained), B1+A1 in flight
  LOAD_A(0);
  GLD_B(0,0);
  CVT_A();                                     // auto-wait A0 (leaves B0)
  LOAD_A(1);
  GLD_B(1,1);
  asm volatile("s_waitcnt vmcnt(12) lgkmcnt(0)" ::: "memory");  // drain B0 + As writes
  __builtin_amdgcn_s_barrier();

  // ---- steady: kt = 0..13
  #pragma unroll 2
  for (int kt=0; kt<14; ++kt){
    const int p = kt&1;
    COMPUTE(p);                                // As(kt), Bs[p]=B(kt)
    __builtin_amdgcn_s_barrier();              // all reads of As/Bs[p] done
    GLD_B(kt+2, p);                            // refill just-freed Bs[p]
    CVT_A();                                   // auto-wait A(kt+1) -> drains B(kt+1) too
    LOAD_A(kt+2);
    asm volatile("s_waitcnt lgkmcnt(0)" ::: "memory");  // As writes visible
    __builtin_amdgcn_s_barrier();
  }
  // ---- tail kt=14
  COMPUTE(0);                                  // As(14), Bs[0]=B14
  __builtin_amdgcn_s_barrier();
  CVT_A();                                     // waits A15 -> drains B15 too
  asm volatile("s_waitcnt lgkmcnt(0)" ::: "memory");
  __builtin_amdgcn_s_barrier();
  // ---- tail kt=15
  COMPUTE(1);                                  // As(15), Bs[1]=B15

  // ---- epilogue: fast-tanh + V_w reduce -> per-bn partial score ----------------
  const int bidx = m0 >> 11;
  float qv[4], vwv[4];
  #pragma unroll
  for (int ni=0;ni<4;ni++){
    int h = h0 + wn + ni*16 + (lane&15);
    qv[ni]  = qb[bidx*H_ + h];
    vwv[ni] = Vw[h];
  }
  __shared__ float psum[4][BM];
  #pragma unroll
  for (int mi=0;mi<4;mi++){
    #pragma unroll
    for (int r=0;r<4;r++){
      float s = 0.f;
      #pragma unroll
      for (int ni=0;ni<4;ni++) s += fast_tanh(acc[mi][ni][r] + qv[ni]) * vwv[ni];
      s += __shfl_xor(s,1); s += __shfl_xor(s,2);
      s += __shfl_xor(s,4); s += __shfl_xor(s,8);
      if ((lane&15)==0){
        int m = wm + mi*16 + ((lane>>4)<<2) + r;
        psum[wave][m] = s;
      }
    }
  }
  __syncthreads();
  if (tid < BM){
    int w0 = (tid>>6)*2;
    score_p[(size_t)bn*M_ + m0 + tid] = psum[w0][tid] + psum[w0+1][tid];
  }
}

// ---------------- kernel 2: masked softmax over S (sums 4 bn partials) -----------
__global__ __launch_bounds__(256) void softmax_kernel(
    const float* __restrict__ score_p, const int* __restrict__ mask,
    float* __restrict__ attn){
  int b = blockIdx.x, tid = threadIdx.x;
  int wave = tid>>6, lane = tid&63;
  __shared__ float red[8];
  float v[8];
  float mx = -1e30f;
  #pragma unroll
  for (int i=0;i<8;i++){
    int idx = b*S_ + tid + i*256;
    float sc = score_p[idx] + score_p[M_+idx] + score_p[2*M_+idx] + score_p[3*M_+idx];
    v[i] = (mask[idx]==0) ? -1e9f : sc;
    mx = fmaxf(mx, v[i]);
  }
  #pragma unroll
  for (int off=1; off<64; off<<=1) mx = fmaxf(mx, __shfl_xor(mx, off));
  if (lane==0) red[wave] = mx;
  __syncthreads();
  mx = fmaxf(fmaxf(red[0],red[1]), fmaxf(red[2],red[3]));
  float sum = 0.f;
  #pragma unroll
  for (int i=0;i<8;i++){ v[i] = __expf(v[i]-mx); sum += v[i]; }
  #pragma unroll
  for (int off=1; off<64; off<<=1) sum += __shfl_xor(sum, off);
  if (lane==0) red[4+wave] = sum;
  __syncthreads();
  float inv = 1.f/(red[4]+red[5]+red[6]+red[7]);
  #pragma unroll
  for (int i=0;i<8;i++) attn[b*S_ + tid + i*256] = v[i]*inv;
}

// ---------------- kernel 3a: context partials (NO atomics, streaming stores) -----
__global__ __launch_bounds__(256) void context_part(
    const float* __restrict__ enc, const float* __restrict__ attn,
    float* __restrict__ ctx_p){
  int b = blockIdx.x, sc = blockIdx.y;        // 32 s-chunks of 64 rows
  int s0 = sc*64;
  int d4 = threadIdx.x*4;
  const float* ep = enc + ((size_t)b*S_ + s0)*D_ + d4;
  const float* ap = attn + b*S_ + s0;
  float4 a0 = make_float4(0.f,0.f,0.f,0.f);
  float4 a1 = make_float4(0.f,0.f,0.f,0.f);
  #pragma unroll 4
  for (int i=0;i<64;i+=2){
    float w0 = ap[i], w1 = ap[i+1];
    float4 e0 = *(const float4*)(ep + (size_t)i*D_);
    float4 e1 = *(const float4*)(ep + (size_t)(i+1)*D_);
    a0.x = fmaf(w0, e0.x, a0.x); a0.y = fmaf(w0, e0.y, a0.y);
    a0.z = fmaf(w0, e0.z, a0.z); a0.w = fmaf(w0, e0.w, a0.w);
    a1.x = fmaf(w1, e1.x, a1.x); a1.y = fmaf(w1, e1.y, a1.y);
    a1.z = fmaf(w1, e1.z, a1.z); a1.w = fmaf(w1, e1.w, a1.w);
  }
  float4 t = make_float4(a0.x+a1.x, a0.y+a1.y, a0.z+a1.z, a0.w+a1.w);
  *(float4*)(ctx_p + ((size_t)b*32 + sc)*D_ + d4) = t;
}

// ---------------- kernel 3b: reduce 32 partials -> ctx ---------------------------
__global__ __launch_bounds__(256) void context_reduce(
    const float* __restrict__ ctx_p, float* __restrict__ ctx){
  int b = blockIdx.x;
  int d4 = threadIdx.x*4;
  f32x4 s = (f32x4)(0.f);
  #pragma unroll 8
  for (int sc=0; sc<32; ++sc)
    s += *(const f32x4*)(ctx_p + ((size_t)b*32 + sc)*D_ + d4);
  *(f32x4*)(ctx + (size_t)b*D_ + d4) = s;
}

extern "C" void kernel_launch(void* const* d_in, const int* in_sizes, int n_in,
                              void* d_out, int out_size, void* d_ws, size_t ws_size,
                              hipStream_t stream){
  const float* hidden = (const float*)d_in[0];
  const float* enc    = (const float*)d_in[1];
  const int*   mask   = (const int*)d_in[2];
  const float* W1w    = (const float*)d_in[3];
  const float* W1b    = (const float*)d_in[4];
  const float* W2w    = (const float*)d_in[5];
  const float* W2b    = (const float*)d_in[6];
  const float* Vw     = (const float*)d_in[7];
  // V_b (d_in[8]) provably cancels in softmax — unused.
  float* out = (float*)d_out;

  float* qb           = (float*)d_ws;                      // 64 KB
  float* score_p      = qb + B_*H_;                        // 4*M_ f32 = 1 MB
  unsigned short* W1s = (unsigned short*)(score_p + 4*M_); // 1 MB bf16 pre-swizzled
  float* ctx_p        = (float*)(W1s + H_*D_);             // 32*32*1024 f32 = 4 MB

  convw_kernel  <<<H_*D_/8/256,     256, 0, stream>>>(W1w, W1s);
  qbias_kernel  <<<dim3(B_, H_/64), 256, 0, stream>>>(hidden, W2w, W1b, W2b, qb);
  score_gemm    <<<4*(M_/BM),       256, 0, stream>>>(enc, W1s, qb, Vw, score_p);
  softmax_kernel<<<B_,              256, 0, stream>>>(score_p, mask, out + B_*D_);
  context_part  <<<dim3(B_, 32),    256, 0, stream>>>(enc, out + B_*D_, ctx_p);
  context_reduce<<<B_,              256, 0, stream>>>(ctx_p, out);
}